// Round 13
// baseline (365.799 us; speedup 1.0000x reference)
//
#include <hip/hip_runtime.h>
#include <hip/hip_bf16.h>
#include <hip/hip_cooperative_groups.h>
#include <math.h>

namespace cg = cooperative_groups;

#define B_ 4
#define T_ 200
#define U_ 100
#define V_ 1024
#define DE 144
#define DD 320
#define J_ 320
#define M_TOT (B_ * T_ * (U_ + 1))  // 80800
#define NTILES 1263                 // ceil(M_TOT/64)
#define SSTR 328                    // LDS row stride (bf16 elems)
#define DSTR 104                    // skewed blank/emit row stride (floats)
#define NDIAG 300                   // t+u in [0, 299]
#define LOG2E 1.4426950408889634f
#define LN2 0.6931471805599453f

typedef __attribute__((ext_vector_type(8))) short bf16x8_t;
typedef __attribute__((ext_vector_type(4))) float f32x4_t;

__device__ __forceinline__ float fast_tanh(float x) {
    float e = exp2f(x * (2.0f * LOG2E));
    float r = __frcp_rn(e + 1.0f);
    return fmaf(-2.0f, r, 1.0f);
}

__device__ __forceinline__ ushort f2bf(float x) {
    uint u = __float_as_uint(x);
    uint r = (u + 0x7FFFu + ((u >> 16) & 1u)) >> 16;
    return (ushort)r;
}

// ---------------------------------------------------------------------------
// Single cooperative kernel: 256 blocks (1/CU) x 1024 thr.
// Phase 1: projections (blocks 0..75) + W_out conversion (blocks 76..255)
// Phase 2: persistent joint GEMM+LSE loop over 1263 tiles (r12 body)
// Phase 3: alpha recursion on block 255
// grid.sync() between phases replaces 2 kernel-launch boundaries.
// ---------------------------------------------------------------------------
__global__ __launch_bounds__(1024, 4) void fused_kernel(
    const float* __restrict__ enc_out, const float* __restrict__ dec_out,
    const float* __restrict__ W_enc, const float* __restrict__ b_enc,
    const float* __restrict__ W_dec, const float* __restrict__ b_dec,
    const float* __restrict__ W_out, const float* __restrict__ b_out,
    const int* __restrict__ targets, const int* __restrict__ enc_len,
    const int* __restrict__ tgt_len,
    float* __restrict__ enc_p, float* __restrict__ dec_p,
    float* __restrict__ bsk, float* __restrict__ esk,
    ushort* __restrict__ Wt, float* __restrict__ out) {
    __shared__ __align__(16) ushort sh[64 * SSTR];   // 41 KB (phase1 reuses as f32)
    __shared__ float parts[16][64];
    __shared__ float lse_sh[64];
    __shared__ int tgt_sh[64];
    __shared__ int skb_sh[64];
    __shared__ float ll_sh[B_];

    cg::grid_group grid = cg::this_grid();
    const int bid = blockIdx.x;
    const int tid = threadIdx.x;

    // ---------------- Phase 1: prep ----------------
    if (bid < 76) {
        const float* X; const float* W; const float* bias; float* Y;
        int K, r0, R;
        if (bid < 50) { X = enc_out; W = W_enc; bias = b_enc; Y = enc_p;
                        K = DE; r0 = bid * 16; R = B_ * T_; }
        else          { X = dec_out; W = W_dec; bias = b_dec; Y = dec_p;
                        K = DD; r0 = (bid - 50) * 16; R = B_ * (U_ + 1); }
        float* sx = (float*)sh;
        const int QK = K >> 2;
        for (int q = tid; q < 16 * QK; q += 1024) {
            int row = q / QK;
            int kq = q - row * QK;
            int r = r0 + row;
            if (r >= R) r = R - 1;
            *(float4*)&sx[row * K + kq * 4] = *(const float4*)&X[r * K + kq * 4];
        }
        __syncthreads();
        if (tid < 640) {
            const int half = (tid >= 320) ? 1 : 0;
            const int c = tid - half * 320;
            float acc[8];
#pragma unroll
            for (int i = 0; i < 8; i++) acc[i] = 0.0f;
            for (int k = 0; k < K; k += 4) {
                float w0 = W[(k + 0) * 320 + c];
                float w1 = W[(k + 1) * 320 + c];
                float w2 = W[(k + 2) * 320 + c];
                float w3 = W[(k + 3) * 320 + c];
#pragma unroll
                for (int i = 0; i < 8; i++) {
                    const float4 x4 = *(const float4*)&sx[(half * 8 + i) * K + k];
                    acc[i] = fmaf(x4.x, w0, acc[i]);
                    acc[i] = fmaf(x4.y, w1, acc[i]);
                    acc[i] = fmaf(x4.z, w2, acc[i]);
                    acc[i] = fmaf(x4.w, w3, acc[i]);
                }
            }
            const float bb = bias[c];
#pragma unroll
            for (int i = 0; i < 8; i++) {
                int r = r0 + half * 8 + i;
                if (r < R) Y[r * 320 + c] = acc[i] + bb;
            }
        }
    } else {
        // W_out (f32 [320][1024]) -> fragment-ordered bf16.
        for (int idx = (bid - 76) * 1024 + tid; idx < J_ * V_; idx += 180 * 1024) {
            int k = idx >> 10;
            int v = idx & 1023;
            ushort b = f2bf(W_out[idx]);
            int frag = (v >> 4) * 10 + (k >> 5);
            int lane = (v & 15) | (((k >> 3) & 3) << 4);
            Wt[frag * 512 + lane * 8 + (k & 7)] = b;
        }
    }
    grid.sync();

    // ---------------- Phase 2: persistent joint ----------------
    const int wave = tid >> 6;
    const int lane = tid & 63;
    const int lrow = lane & 15;
    const int lk = (lane >> 4) * 8;
    const int cb16 = wave * 4;
    float bo4[4], boL[4];
#pragma unroll
    for (int nt = 0; nt < 4; nt++) {
        float b = b_out[wave * 64 + nt * 16 + lrow];
        bo4[nt] = b;
        boL[nt] = b * LOG2E;
    }

    for (int tile = bid; tile < NTILES; tile += 256) {
        const int r0 = tile * 64;

        if (tid < 64) {
            int rc = r0 + tid;
            int tg = -1, skb = -1;
            if (rc < M_TOT) {
                int b = rc / 20200;
                int rem = rc - b * 20200;
                int t = rem / 101;
                int u = rem - t * 101;
                skb = (b * NDIAG + t + u) * DSTR + u;
                if (u < U_) tg = targets[b * U_ + u];
            }
            tgt_sh[tid] = tg;
            skb_sh[tid] = skb;
        }
        // Stage h = tanh(enc_p + dec_p) as bf16 into LDS.
        {
            const int si = tid >> 4;
            const int sq = tid & 15;
            int rc = r0 + si;
            if (rc > M_TOT - 1) rc = M_TOT - 1;
            int b = rc / 20200;
            int rem = rc - b * 20200;
            int t = rem / 101;
            int u = rem - t * 101;
            const float4* ep = (const float4*)&enc_p[(b * 200 + t) * 320];
            const float4* dp = (const float4*)&dec_p[(b * 101 + u) * 320];
            ushort* shp = &sh[si * SSTR];
#pragma unroll
            for (int it = 0; it < 5; it++) {
                int kq = sq + it * 16;
                float4 e = ep[kq];
                float4 dd = dp[kq];
                float t0 = fast_tanh(e.x + dd.x);
                float t1 = fast_tanh(e.y + dd.y);
                float t2 = fast_tanh(e.z + dd.z);
                float t3 = fast_tanh(e.w + dd.w);
                __hip_bfloat162 p0 = __float22bfloat162_rn(make_float2(t0, t1));
                __hip_bfloat162 p1 = __float22bfloat162_rn(make_float2(t2, t3));
                uint2 pk;
                pk.x = *(uint*)&p0;
                pk.y = *(uint*)&p1;
                *(uint2*)&shp[kq * 4] = pk;
            }
        }
        __syncthreads();

        f32x4_t acc[4][4];
#pragma unroll
        for (int mt = 0; mt < 4; mt++)
#pragma unroll
            for (int nt = 0; nt < 4; nt++) acc[mt][nt] = (f32x4_t)(0.0f);

        for (int ks = 0; ks < 10; ks++) {
            bf16x8_t a[4];
#pragma unroll
            for (int mt = 0; mt < 4; mt++)
                a[mt] = *(const bf16x8_t*)&sh[(mt * 16 + lrow) * SSTR + ks * 32 + lk];
#pragma unroll
            for (int nt = 0; nt < 4; nt++) {
                bf16x8_t bfr = *(const bf16x8_t*)&Wt[(((cb16 + nt) * 10 + ks) << 9) + lane * 8];
                __builtin_amdgcn_s_setprio(1);
#pragma unroll
                for (int mt = 0; mt < 4; mt++)
                    acc[mt][nt] = __builtin_amdgcn_mfma_f32_16x16x32_bf16(a[mt], bfr, acc[mt][nt], 0, 0, 0);
                __builtin_amdgcn_s_setprio(0);
            }
        }

        // Row LSE, no max-pass; bias folded into exp via boL.
#pragma unroll
        for (int mt = 0; mt < 4; mt++) {
#pragma unroll
            for (int j = 0; j < 4; j++) {
                float s = exp2f(fmaf(acc[mt][0][j], LOG2E, boL[0]));
                s += exp2f(fmaf(acc[mt][1][j], LOG2E, boL[1]));
                s += exp2f(fmaf(acc[mt][2][j], LOG2E, boL[2]));
                s += exp2f(fmaf(acc[mt][3][j], LOG2E, boL[3]));
#pragma unroll
                for (int off = 1; off < 16; off <<= 1)
                    s += __shfl_xor(s, off, 16);
                if (lrow == 0) {
                    int row = mt * 16 + (lane >> 4) * 4 + j;
                    parts[wave][row] = s;
                }
            }
        }
        __syncthreads();
        if (tid < 64) {
            float s = parts[0][tid];
#pragma unroll
            for (int w = 1; w < 16; w++) s += parts[w][tid];
            lse_sh[tid] = __log2f(s) * LN2;
        }
        __syncthreads();

        // Write blank (col 0) and emit (target col) via precomputed skew base
#pragma unroll
        for (int mt = 0; mt < 4; mt++) {
#pragma unroll
            for (int j = 0; j < 4; j++) {
                int lr = mt * 16 + (lane >> 4) * 4 + j;
                int skb = skb_sh[lr];
                if (skb < 0) continue;
                int tc = tgt_sh[lr];
                bool isblank = (wave == 0) && (lrow == 0);
                bool isemit = (tc >= 0) && ((tc >> 6) == wave) && ((tc & 15) == lrow);
                if (isblank || isemit) {
                    float lse = lse_sh[lr];
                    if (isblank) bsk[skb] = acc[mt][0][j] + bo4[0] - lse;
                    if (isemit) {
                        int ntl = (tc >> 4) & 3;
                        float v = acc[mt][0][j] + bo4[0];
#pragma unroll
                        for (int nt = 1; nt < 4; nt++)
                            if (nt == ntl) v = acc[mt][nt][j] + bo4[nt];
                        esk[skb] = v - lse;
                    }
                }
            }
        }
        __syncthreads();  // protect sh/tgt_sh/skb_sh/parts/lse_sh for next tile
    }
    grid.sync();

    // ---------------- Phase 3: alpha recursion (block 255) ----------------
    if (bid == 255) {
        if (tid < 256) {
            const int b = tid >> 6;
            const int l = tid & 63;
            const float* Bp = bsk + b * (NDIAG * DSTR);
            const float* Ep = esk + b * (NDIAG * DSTR);
            const int el = enc_len[b];
            const int tl = tgt_len[b];
            const int dfin = el - 1 + tl;

            const int u0 = 2 * l;
            const bool ok0 = (u0 <= U_);
            const bool ok1 = (u0 + 1 <= U_);
            const int uc = ok0 ? u0 : 0;

            float A0 = (l == 0) ? 0.0f : -INFINITY;
            float A1 = -INFINITY;

            float2 rb[16], re[16];
#pragma unroll
            for (int k = 0; k < 16; k++) {
                rb[k] = *(const float2*)&Bp[k * DSTR + uc];
                re[k] = *(const float2*)&Ep[k * DSTR + uc];
            }

            for (int dc = 1; dc <= 289; dc += 16) {
#pragma unroll
                for (int q = 0; q < 16; q++) {
                    const int d = dc + q;
                    if (d > NDIAG - 1) continue;
                    const int sc = q;
                    const int sm = (q + 1) & 15;
                    float2 cb = rb[sc], ce = re[sc];
                    float2 mb = rb[sm];
                    int dn = d + 15;
                    if (dn > NDIAG - 1) dn = NDIAG - 1;
                    rb[sc] = *(const float2*)&Bp[dn * DSTR + uc];
                    re[sc] = *(const float2*)&Ep[dn * DSTR + uc];

                    float s = A1 + ce.y;
                    float sn = __shfl_up(s, 1, 64);

                    float va0 = A0 + cb.x;
                    float vb0 = (l >= 1) ? sn : -INFINITY;
                    float va1 = A1 + cb.y;
                    float vb1 = A0 + ce.x;

                    float M0 = fmaxf(va0, vb0);
                    float n0 = (M0 == -INFINITY)
                                   ? -INFINITY
                                   : M0 + __logf(1.0f + __expf(fminf(va0, vb0) - M0));
                    float M1 = fmaxf(va1, vb1);
                    float n1 = (M1 == -INFINITY)
                                   ? -INFINITY
                                   : M1 + __logf(1.0f + __expf(fminf(va1, vb1) - M1));

                    const int t0 = d - u0;
                    if (!ok0 || t0 < 0 || t0 >= T_) n0 = -INFINITY;
                    if (!ok1 || (t0 - 1) < 0 || (t0 - 1) >= T_) n1 = -INFINITY;

                    if (d == dfin) {
                        if (tl == u0) ll_sh[b] = n0 + mb.x;
                        if (tl == u0 + 1) ll_sh[b] = n1 + mb.y;
                    }
                    A0 = n0;
                    A1 = n1;
                }
            }
        }
        __syncthreads();
        if (tid == 0)
            out[0] = -0.25f * (ll_sh[0] + ll_sh[1] + ll_sh[2] + ll_sh[3]);
    }
}

extern "C" void kernel_launch(void* const* d_in, const int* in_sizes, int n_in,
                              void* d_out, int out_size, void* d_ws, size_t ws_size,
                              hipStream_t stream) {
    const float* enc_out = (const float*)d_in[0];
    const float* dec_out = (const float*)d_in[1];
    const float* W_enc = (const float*)d_in[2];
    const float* b_enc = (const float*)d_in[3];
    const float* W_dec = (const float*)d_in[4];
    const float* b_dec = (const float*)d_in[5];
    const float* W_out = (const float*)d_in[6];
    const float* b_out = (const float*)d_in[7];
    const int* targets = (const int*)d_in[8];
    const int* enc_len = (const int*)d_in[9];
    const int* tgt_len = (const int*)d_in[10];

    float* ws = (float*)d_ws;
    float* enc_p = ws;                          // 256000 f32
    float* dec_p = enc_p + B_ * T_ * J_;        // 129280 f32
    float* bsk = dec_p + B_ * (U_ + 1) * J_;    // 124800 f32
    float* esk = bsk + B_ * NDIAG * DSTR;       // 124800 f32
    ushort* Wt = (ushort*)(esk + B_ * NDIAG * DSTR);  // 327680 bf16
    float* outp = (float*)d_out;

    void* args[] = {(void*)&enc_out, (void*)&dec_out, (void*)&W_enc,
                    (void*)&b_enc,   (void*)&W_dec,   (void*)&b_dec,
                    (void*)&W_out,   (void*)&b_out,   (void*)&targets,
                    (void*)&enc_len, (void*)&tgt_len, (void*)&enc_p,
                    (void*)&dec_p,   (void*)&bsk,     (void*)&esk,
                    (void*)&Wt,      (void*)&outp};
    hipLaunchCooperativeKernel((const void*)fused_kernel, dim3(256), dim3(1024),
                               args, 0, stream);
}

// Round 14
// 193.227 us; speedup vs baseline: 1.8931x; 1.8931x over previous
//
#include <hip/hip_runtime.h>
#include <hip/hip_bf16.h>
#include <math.h>

#define B_ 4
#define T_ 200
#define U_ 100
#define V_ 1024
#define DE 144
#define DD 320
#define J_ 320
#define M_TOT (B_ * T_ * (U_ + 1))  // 80800
#define SSTR 328                    // LDS row stride (bf16 elems)
#define DSTR 104                    // skewed blank/emit row stride (floats)
#define NDIAG 300                   // t+u in [0, 299]
#define LOG2E 1.4426950408889634f
#define LN2 0.6931471805599453f

typedef __attribute__((ext_vector_type(8))) short bf16x8_t;
typedef __attribute__((ext_vector_type(4))) float f32x4_t;

__device__ __forceinline__ float fast_tanh(float x) {
    // tanh(x) = 1 - 2/(e^{2x}+1); raw v_rcp_f32 (~1 ulp) is fine at 2% tol.
    float e = exp2f(x * (2.0f * LOG2E));
    float r = __builtin_amdgcn_rcpf(e + 1.0f);
    return fmaf(-2.0f, r, 1.0f);
}

__device__ __forceinline__ ushort f2bf(float x) {
    uint u = __float_as_uint(x);
    uint r = (u + 0x7FFFu + ((u >> 16) & 1u)) >> 16;
    return (ushort)r;
}

// ---------------------------------------------------------------------------
// Tiled fp32 projection: 16 rows x 320 cols per block, 640 threads.
// ---------------------------------------------------------------------------
template <int K>
__device__ __forceinline__ void proj_body(const float* __restrict__ X,
                                          const float* __restrict__ W,
                                          const float* __restrict__ bias,
                                          float* __restrict__ Y,
                                          int r0, int R, float* sx, int tid) {
    constexpr int QK = K / 4;
    for (int q = tid; q < 16 * QK; q += 640) {
        int row = q / QK;
        int kq = q - row * QK;
        int r = r0 + row;
        if (r >= R) r = R - 1;
        *(float4*)&sx[row * K + kq * 4] = *(const float4*)&X[r * K + kq * 4];
    }
    __syncthreads();
    const int half = (tid >= 320) ? 1 : 0;
    const int c = tid - half * 320;
    float acc[8];
#pragma unroll
    for (int i = 0; i < 8; i++) acc[i] = 0.0f;
    for (int k = 0; k < K; k += 4) {
        float w0 = W[(k + 0) * 320 + c];
        float w1 = W[(k + 1) * 320 + c];
        float w2 = W[(k + 2) * 320 + c];
        float w3 = W[(k + 3) * 320 + c];
#pragma unroll
        for (int i = 0; i < 8; i++) {
            const float4 x4 = *(const float4*)&sx[(half * 8 + i) * K + k];
            acc[i] = fmaf(x4.x, w0, acc[i]);
            acc[i] = fmaf(x4.y, w1, acc[i]);
            acc[i] = fmaf(x4.z, w2, acc[i]);
            acc[i] = fmaf(x4.w, w3, acc[i]);
        }
    }
    const float bb = bias[c];
#pragma unroll
    for (int i = 0; i < 8; i++) {
        int r = r0 + half * 8 + i;
        if (r < R) Y[r * 320 + c] = acc[i] + bb;
    }
}

// grid: [0,50) proj_enc | [50,76) proj_dec | [76,140) wconv (output-linear)
__global__ __launch_bounds__(640) void prep_kernel(
    const float* __restrict__ enc_out, const float* __restrict__ dec_out,
    const float* __restrict__ W_enc, const float* __restrict__ b_enc,
    const float* __restrict__ W_dec, const float* __restrict__ b_dec,
    const float* __restrict__ W_out,
    float* __restrict__ enc_p, float* __restrict__ dec_p,
    ushort* __restrict__ Wt) {
    __shared__ float sx[16 * 320];
    const int bid = blockIdx.x;
    const int tid = threadIdx.x;
    if (bid < 50) {
        proj_body<DE>(enc_out, W_enc, b_enc, enc_p, bid * 16, B_ * T_, sx, tid);
    } else if (bid < 76) {
        proj_body<DD>(dec_out, W_dec, b_dec, dec_p, (bid - 50) * 16,
                      B_ * (U_ + 1), sx, tid);
    } else {
        // W_out (f32 [320][1024]) -> fragment-ordered bf16, output-linear:
        // each thread emits 8 consecutive bf16 (one frag-lane row, 16B).
        int o8 = (bid - 76) * 640 + tid;   // 0..40959
        int frag = o8 >> 6;                // 512 elems/frag = 64 rows of 8
        int lane8 = o8 & 63;
        int fv = frag / 10;
        int fk = frag - fv * 10;
        int v = fv * 16 + (lane8 & 15);
        int kbase = fk * 32 + ((lane8 >> 4) << 3);
        ushort tmp[8];
#pragma unroll
        for (int e = 0; e < 8; e++) tmp[e] = f2bf(W_out[(kbase + e) * 1024 + v]);
        *(ushort4*)&Wt[o8 * 8] = *(ushort4*)&tmp[0];
        *(ushort4*)&Wt[o8 * 8 + 4] = *(ushort4*)&tmp[4];
    }
}

// ---------------------------------------------------------------------------
// Joint kernel (r12 structure): 1024 thr (16 waves), 64 rows x 1024 cols.
// Wave w owns cols [64w, 64w+64). Per-row decode hoisted to LDS tables.
// No setprio (null-to-negative for barrier-lockstep GEMM, m190).
// ---------------------------------------------------------------------------
__global__ __launch_bounds__(1024, 4) void joint_mfma(
    const float* __restrict__ enc_p, const float* __restrict__ dec_p,
    const ushort* __restrict__ Wt, const float* __restrict__ b_out,
    const int* __restrict__ targets,
    float* __restrict__ bsk, float* __restrict__ esk) {
    __shared__ ushort sh[64 * SSTR];
    __shared__ float parts[16][64];
    __shared__ float lse_sh[64];
    __shared__ int tgt_sh[64];
    __shared__ int skb_sh[64];

    const int tid = threadIdx.x;
    const int r0 = blockIdx.x * 64;

    // Hoisted per-row decode: target + skewed base index
    if (tid < 64) {
        int rc = r0 + tid;
        int tg = -1, skb = -1;
        if (rc < M_TOT) {
            int b = rc / 20200;
            int rem = rc - b * 20200;
            int t = rem / 101;
            int u = rem - t * 101;
            skb = (b * NDIAG + t + u) * DSTR + u;
            if (u < U_) tg = targets[b * U_ + u];
        }
        tgt_sh[tid] = tg;
        skb_sh[tid] = skb;
    }

    // Stage h = tanh(enc_p + dec_p) as bf16 into LDS.
    {
        const int si = tid >> 4;
        const int sq = tid & 15;
        int rc = r0 + si;
        if (rc > M_TOT - 1) rc = M_TOT - 1;
        int b = rc / 20200;
        int rem = rc - b * 20200;
        int t = rem / 101;
        int u = rem - t * 101;
        const float4* ep = (const float4*)&enc_p[(b * 200 + t) * 320];
        const float4* dp = (const float4*)&dec_p[(b * 101 + u) * 320];
        ushort* shp = &sh[si * SSTR];
#pragma unroll
        for (int it = 0; it < 5; it++) {
            int kq = sq + it * 16;
            float4 e = ep[kq];
            float4 dd = dp[kq];
            float t0 = fast_tanh(e.x + dd.x);
            float t1 = fast_tanh(e.y + dd.y);
            float t2 = fast_tanh(e.z + dd.z);
            float t3 = fast_tanh(e.w + dd.w);
            __hip_bfloat162 p0 = __float22bfloat162_rn(make_float2(t0, t1));
            __hip_bfloat162 p1 = __float22bfloat162_rn(make_float2(t2, t3));
            uint2 pk;
            pk.x = *(uint*)&p0;
            pk.y = *(uint*)&p1;
            *(uint2*)&shp[kq * 4] = pk;
        }
    }
    __syncthreads();

    const int wave = tid >> 6;
    const int lane = tid & 63;
    const int lrow = lane & 15;
    const int lk = (lane >> 4) * 8;
    const int cb16 = wave * 4;

    f32x4_t acc[4][4];
#pragma unroll
    for (int mt = 0; mt < 4; mt++)
#pragma unroll
        for (int nt = 0; nt < 4; nt++) acc[mt][nt] = (f32x4_t)(0.0f);

    for (int ks = 0; ks < 10; ks++) {
        bf16x8_t a[4];
#pragma unroll
        for (int mt = 0; mt < 4; mt++)
            a[mt] = *(const bf16x8_t*)&sh[(mt * 16 + lrow) * SSTR + ks * 32 + lk];
#pragma unroll
        for (int nt = 0; nt < 4; nt++) {
            bf16x8_t bfr = *(const bf16x8_t*)&Wt[(((cb16 + nt) * 10 + ks) << 9) + lane * 8];
#pragma unroll
            for (int mt = 0; mt < 4; mt++)
                acc[mt][nt] = __builtin_amdgcn_mfma_f32_16x16x32_bf16(a[mt], bfr, acc[mt][nt], 0, 0, 0);
        }
    }

    // Bias
    float bo[4];
#pragma unroll
    for (int nt = 0; nt < 4; nt++) bo[nt] = b_out[wave * 64 + nt * 16 + lrow];
#pragma unroll
    for (int mt = 0; mt < 4; mt++)
#pragma unroll
        for (int nt = 0; nt < 4; nt++) acc[mt][nt] += bo[nt];

    // Row LSE, no max-pass: s = sum exp2(l*log2e), shfl-add over 16 lanes.
#pragma unroll
    for (int mt = 0; mt < 4; mt++) {
#pragma unroll
        for (int j = 0; j < 4; j++) {
            float s = exp2f(acc[mt][0][j] * LOG2E);
            s += exp2f(acc[mt][1][j] * LOG2E);
            s += exp2f(acc[mt][2][j] * LOG2E);
            s += exp2f(acc[mt][3][j] * LOG2E);
#pragma unroll
            for (int off = 1; off < 16; off <<= 1)
                s += __shfl_xor(s, off, 16);
            if (lrow == 0) {
                int row = mt * 16 + (lane >> 4) * 4 + j;
                parts[wave][row] = s;
            }
        }
    }
    __syncthreads();
    if (tid < 64) {
        float s = parts[0][tid];
#pragma unroll
        for (int w = 1; w < 16; w++) s += parts[w][tid];
        lse_sh[tid] = __log2f(s) * LN2;
    }
    __syncthreads();

    // Write blank (col 0) and emit (target col) via precomputed skew base
#pragma unroll
    for (int mt = 0; mt < 4; mt++) {
#pragma unroll
        for (int j = 0; j < 4; j++) {
            int lr = mt * 16 + (lane >> 4) * 4 + j;
            int skb = skb_sh[lr];
            if (skb < 0) continue;
            int tc = tgt_sh[lr];
            bool isblank = (wave == 0) && (lrow == 0);
            bool isemit = (tc >= 0) && ((tc >> 6) == wave) && ((tc & 15) == lrow);
            if (isblank || isemit) {
                float lse = lse_sh[lr];
                if (isblank) bsk[skb] = acc[mt][0][j] - lse;
                if (isemit) {
                    int ntl = (tc >> 4) & 3;
                    float v = acc[mt][0][j];
#pragma unroll
                    for (int nt = 1; nt < 4; nt++)
                        if (nt == ntl) v = acc[mt][nt][j];
                    esk[skb] = v - lse;
                }
            }
        }
    }
}

// ---------------------------------------------------------------------------
// Alpha recursion, u-chunk x2, 16-deep prefetch ring (slack > HBM latency).
// __launch_bounds__(256,1): full register budget, ring stays in VGPRs.
// ---------------------------------------------------------------------------
__global__ __launch_bounds__(256, 1) void alpha_c2_kernel(
    const float* __restrict__ bsk, const float* __restrict__ esk,
    const int* __restrict__ enc_len, const int* __restrict__ tgt_len,
    float* __restrict__ out) {
    __shared__ float ll_sh[B_];
    const int tid = threadIdx.x;
    const int b = tid >> 6;
    const int l = tid & 63;
    const float* Bp = bsk + b * (NDIAG * DSTR);
    const float* Ep = esk + b * (NDIAG * DSTR);
    const int el = enc_len[b];
    const int tl = tgt_len[b];
    const int dfin = el - 1 + tl;

    const int u0 = 2 * l;
    const bool ok0 = (u0 <= U_);
    const bool ok1 = (u0 + 1 <= U_);
    const int uc = ok0 ? u0 : 0;

    float A0 = (l == 0) ? 0.0f : -INFINITY;
    float A1 = -INFINITY;

    float2 rb[16], re[16];
#pragma unroll
    for (int k = 0; k < 16; k++) {
        rb[k] = *(const float2*)&Bp[k * DSTR + uc];
        re[k] = *(const float2*)&Ep[k * DSTR + uc];
    }

    for (int dc = 1; dc <= 289; dc += 16) {
#pragma unroll
        for (int q = 0; q < 16; q++) {
            const int d = dc + q;  // (dc-1)%16==0 -> static slot indices
            if (d > NDIAG - 1) continue;
            const int sc = q;             // (d-1)&15
            const int sm = (q + 1) & 15;  // d&15
            float2 cb = rb[sc], ce = re[sc];
            float2 mb = rb[sm];
            int dn = d + 15;
            if (dn > NDIAG - 1) dn = NDIAG - 1;
            rb[sc] = *(const float2*)&Bp[dn * DSTR + uc];
            re[sc] = *(const float2*)&Ep[dn * DSTR + uc];

            float s = A1 + ce.y;
            float sn = __shfl_up(s, 1, 64);

            float va0 = A0 + cb.x;
            float vb0 = (l >= 1) ? sn : -INFINITY;
            float va1 = A1 + cb.y;
            float vb1 = A0 + ce.x;

            float M0 = fmaxf(va0, vb0);
            float n0 = (M0 == -INFINITY)
                           ? -INFINITY
                           : M0 + __logf(1.0f + __expf(fminf(va0, vb0) - M0));
            float M1 = fmaxf(va1, vb1);
            float n1 = (M1 == -INFINITY)
                           ? -INFINITY
                           : M1 + __logf(1.0f + __expf(fminf(va1, vb1) - M1));

            const int t0 = d - u0;
            if (!ok0 || t0 < 0 || t0 >= T_) n0 = -INFINITY;
            if (!ok1 || (t0 - 1) < 0 || (t0 - 1) >= T_) n1 = -INFINITY;

            if (d == dfin) {
                if (tl == u0) ll_sh[b] = n0 + mb.x;
                if (tl == u0 + 1) ll_sh[b] = n1 + mb.y;
            }
            A0 = n0;
            A1 = n1;
        }
    }
    __syncthreads();
    if (tid == 0)
        out[0] = -0.25f * (ll_sh[0] + ll_sh[1] + ll_sh[2] + ll_sh[3]);
}

extern "C" void kernel_launch(void* const* d_in, const int* in_sizes, int n_in,
                              void* d_out, int out_size, void* d_ws, size_t ws_size,
                              hipStream_t stream) {
    const float* enc_out = (const float*)d_in[0];
    const float* dec_out = (const float*)d_in[1];
    const float* W_enc = (const float*)d_in[2];
    const float* b_enc = (const float*)d_in[3];
    const float* W_dec = (const float*)d_in[4];
    const float* b_dec = (const float*)d_in[5];
    const float* W_out = (const float*)d_in[6];
    const float* b_out = (const float*)d_in[7];
    const int* targets = (const int*)d_in[8];
    const int* enc_len = (const int*)d_in[9];
    const int* tgt_len = (const int*)d_in[10];

    float* ws = (float*)d_ws;
    float* enc_p = ws;                          // 256000 f32
    float* dec_p = enc_p + B_ * T_ * J_;        // 129280 f32
    float* bsk = dec_p + B_ * (U_ + 1) * J_;    // 124800 f32
    float* esk = bsk + B_ * NDIAG * DSTR;       // 124800 f32
    ushort* Wt = (ushort*)(esk + B_ * NDIAG * DSTR);  // 327680 bf16

    prep_kernel<<<140, 640, 0, stream>>>(enc_out, dec_out, W_enc, b_enc,
                                         W_dec, b_dec, W_out, enc_p, dec_p, Wt);

    joint_mfma<<<(M_TOT + 63) / 64, 1024, 0, stream>>>(
        enc_p, dec_p, Wt, b_out, targets, bsk, esk);

    alpha_c2_kernel<<<1, 256, 0, stream>>>(bsk, esk, enc_len, tgt_len,
                                           (float*)d_out);
}

// Round 15
// 191.707 us; speedup vs baseline: 1.9081x; 1.0079x over previous
//
#include <hip/hip_runtime.h>
#include <hip/hip_bf16.h>
#include <math.h>

#define B_ 4
#define T_ 200
#define U_ 100
#define V_ 1024
#define DE 144
#define DD 320
#define J_ 320
#define M_TOT (B_ * T_ * (U_ + 1))  // 80800
#define SSTR 328                    // LDS row stride (bf16 elems)
#define DSTR 104                    // skewed blank/emit row stride (floats)
#define NDIAG 300                   // t+u in [0, 299]
#define LOG2E 1.4426950408889634f
#define LN2 0.6931471805599453f

typedef __attribute__((ext_vector_type(8))) short bf16x8_t;
typedef __attribute__((ext_vector_type(4))) float f32x4_t;

__device__ __forceinline__ float fast_tanh(float x) {
    // tanh(x) = 1 - 2/(e^{2x}+1); raw v_exp/v_rcp (~1 ulp) fine at 2% tol.
    float e = __builtin_amdgcn_exp2f(x * (2.0f * LOG2E));
    float r = __builtin_amdgcn_rcpf(e + 1.0f);
    return fmaf(-2.0f, r, 1.0f);
}

__device__ __forceinline__ ushort f2bf(float x) {
    uint u = __float_as_uint(x);
    uint r = (u + 0x7FFFu + ((u >> 16) & 1u)) >> 16;
    return (ushort)r;
}

// ---------------------------------------------------------------------------
// Tiled fp32 projection: 16 rows x 320 cols per block, 640 threads.
// ---------------------------------------------------------------------------
template <int K>
__device__ __forceinline__ void proj_body(const float* __restrict__ X,
                                          const float* __restrict__ W,
                                          const float* __restrict__ bias,
                                          float* __restrict__ Y,
                                          int r0, int R, float* sx, int tid) {
    constexpr int QK = K / 4;
    for (int q = tid; q < 16 * QK; q += 640) {
        int row = q / QK;
        int kq = q - row * QK;
        int r = r0 + row;
        if (r >= R) r = R - 1;
        *(float4*)&sx[row * K + kq * 4] = *(const float4*)&X[r * K + kq * 4];
    }
    __syncthreads();
    const int half = (tid >= 320) ? 1 : 0;
    const int c = tid - half * 320;
    float acc[8];
#pragma unroll
    for (int i = 0; i < 8; i++) acc[i] = 0.0f;
    for (int k = 0; k < K; k += 4) {
        float w0 = W[(k + 0) * 320 + c];
        float w1 = W[(k + 1) * 320 + c];
        float w2 = W[(k + 2) * 320 + c];
        float w3 = W[(k + 3) * 320 + c];
#pragma unroll
        for (int i = 0; i < 8; i++) {
            const float4 x4 = *(const float4*)&sx[(half * 8 + i) * K + k];
            acc[i] = fmaf(x4.x, w0, acc[i]);
            acc[i] = fmaf(x4.y, w1, acc[i]);
            acc[i] = fmaf(x4.z, w2, acc[i]);
            acc[i] = fmaf(x4.w, w3, acc[i]);
        }
    }
    const float bb = bias[c];
#pragma unroll
    for (int i = 0; i < 8; i++) {
        int r = r0 + half * 8 + i;
        if (r < R) Y[r * 320 + c] = acc[i] + bb;
    }
}

// grid: [0,50) proj_enc | [50,76) proj_dec | [76,140) wconv (output-linear)
__global__ __launch_bounds__(640) void prep_kernel(
    const float* __restrict__ enc_out, const float* __restrict__ dec_out,
    const float* __restrict__ W_enc, const float* __restrict__ b_enc,
    const float* __restrict__ W_dec, const float* __restrict__ b_dec,
    const float* __restrict__ W_out,
    float* __restrict__ enc_p, float* __restrict__ dec_p,
    ushort* __restrict__ Wt) {
    __shared__ float sx[16 * 320];
    const int bid = blockIdx.x;
    const int tid = threadIdx.x;
    if (bid < 50) {
        proj_body<DE>(enc_out, W_enc, b_enc, enc_p, bid * 16, B_ * T_, sx, tid);
    } else if (bid < 76) {
        proj_body<DD>(dec_out, W_dec, b_dec, dec_p, (bid - 50) * 16,
                      B_ * (U_ + 1), sx, tid);
    } else {
        // W_out (f32 [320][1024]) -> fragment-ordered bf16, output-linear:
        // each thread emits 8 consecutive bf16 (one frag-lane row, 16B).
        int o8 = (bid - 76) * 640 + tid;   // 0..40959
        int frag = o8 >> 6;                // 512 elems/frag = 64 rows of 8
        int lane8 = o8 & 63;
        int fv = frag / 10;
        int fk = frag - fv * 10;
        int v = fv * 16 + (lane8 & 15);
        int kbase = fk * 32 + ((lane8 >> 4) << 3);
        ushort tmp[8];
#pragma unroll
        for (int e = 0; e < 8; e++) tmp[e] = f2bf(W_out[(kbase + e) * 1024 + v]);
        *(ushort4*)&Wt[o8 * 8] = *(ushort4*)&tmp[0];
        *(ushort4*)&Wt[o8 * 8 + 4] = *(ushort4*)&tmp[4];
    }
}

// ---------------------------------------------------------------------------
// Joint kernel (r12 structure, slim epilogue): 1024 thr (16 waves),
// 64 rows x 1024 cols. Wave w owns cols [64w, 64w+64).
// Bias folded into exp arg (boL = bias*log2e): acc never modified, no
// 64-add + AGPR write-back pass. Register-neutral (boL replaces bo).
// ---------------------------------------------------------------------------
__global__ __launch_bounds__(1024, 4) void joint_mfma(
    const float* __restrict__ enc_p, const float* __restrict__ dec_p,
    const ushort* __restrict__ Wt, const float* __restrict__ b_out,
    const int* __restrict__ targets,
    float* __restrict__ bsk, float* __restrict__ esk) {
    __shared__ ushort sh[64 * SSTR];
    __shared__ float parts[16][64];
    __shared__ float lse_sh[64];
    __shared__ int tgt_sh[64];
    __shared__ int skb_sh[64];

    const int tid = threadIdx.x;
    const int r0 = blockIdx.x * 64;

    // Hoisted per-row decode: target + skewed base index
    if (tid < 64) {
        int rc = r0 + tid;
        int tg = -1, skb = -1;
        if (rc < M_TOT) {
            int b = rc / 20200;
            int rem = rc - b * 20200;
            int t = rem / 101;
            int u = rem - t * 101;
            skb = (b * NDIAG + t + u) * DSTR + u;
            if (u < U_) tg = targets[b * U_ + u];
        }
        tgt_sh[tid] = tg;
        skb_sh[tid] = skb;
    }

    // Stage h = tanh(enc_p + dec_p) as bf16 into LDS.
    {
        const int si = tid >> 4;
        const int sq = tid & 15;
        int rc = r0 + si;
        if (rc > M_TOT - 1) rc = M_TOT - 1;
        int b = rc / 20200;
        int rem = rc - b * 20200;
        int t = rem / 101;
        int u = rem - t * 101;
        const float4* ep = (const float4*)&enc_p[(b * 200 + t) * 320];
        const float4* dp = (const float4*)&dec_p[(b * 101 + u) * 320];
        ushort* shp = &sh[si * SSTR];
#pragma unroll
        for (int it = 0; it < 5; it++) {
            int kq = sq + it * 16;
            float4 e = ep[kq];
            float4 dd = dp[kq];
            float t0 = fast_tanh(e.x + dd.x);
            float t1 = fast_tanh(e.y + dd.y);
            float t2 = fast_tanh(e.z + dd.z);
            float t3 = fast_tanh(e.w + dd.w);
            __hip_bfloat162 p0 = __float22bfloat162_rn(make_float2(t0, t1));
            __hip_bfloat162 p1 = __float22bfloat162_rn(make_float2(t2, t3));
            uint2 pk;
            pk.x = *(uint*)&p0;
            pk.y = *(uint*)&p1;
            *(uint2*)&shp[kq * 4] = pk;
        }
    }
    __syncthreads();

    const int wave = tid >> 6;
    const int lane = tid & 63;
    const int lrow = lane & 15;
    const int lk = (lane >> 4) * 8;
    const int cb16 = wave * 4;

    f32x4_t acc[4][4];
#pragma unroll
    for (int mt = 0; mt < 4; mt++)
#pragma unroll
        for (int nt = 0; nt < 4; nt++) acc[mt][nt] = (f32x4_t)(0.0f);

    for (int ks = 0; ks < 10; ks++) {
        bf16x8_t a[4];
#pragma unroll
        for (int mt = 0; mt < 4; mt++)
            a[mt] = *(const bf16x8_t*)&sh[(mt * 16 + lrow) * SSTR + ks * 32 + lk];
#pragma unroll
        for (int nt = 0; nt < 4; nt++) {
            bf16x8_t bfr = *(const bf16x8_t*)&Wt[(((cb16 + nt) * 10 + ks) << 9) + lane * 8];
#pragma unroll
            for (int mt = 0; mt < 4; mt++)
                acc[mt][nt] = __builtin_amdgcn_mfma_f32_16x16x32_bf16(a[mt], bfr, acc[mt][nt], 0, 0, 0);
        }
    }

    // Bias in log2-domain only (boL = bias * log2e); acc left untouched.
    float boL[4];
#pragma unroll
    for (int nt = 0; nt < 4; nt++)
        boL[nt] = b_out[wave * 64 + nt * 16 + lrow] * LOG2E;

    // Row LSE, no max-pass: s = sum exp2(acc*log2e + boL), shfl-add over 16.
#pragma unroll
    for (int mt = 0; mt < 4; mt++) {
#pragma unroll
        for (int j = 0; j < 4; j++) {
            float s = __builtin_amdgcn_exp2f(fmaf(acc[mt][0][j], LOG2E, boL[0]));
            s += __builtin_amdgcn_exp2f(fmaf(acc[mt][1][j], LOG2E, boL[1]));
            s += __builtin_amdgcn_exp2f(fmaf(acc[mt][2][j], LOG2E, boL[2]));
            s += __builtin_amdgcn_exp2f(fmaf(acc[mt][3][j], LOG2E, boL[3]));
#pragma unroll
            for (int off = 1; off < 16; off <<= 1)
                s += __shfl_xor(s, off, 16);
            if (lrow == 0) {
                int row = mt * 16 + (lane >> 4) * 4 + j;
                parts[wave][row] = s;
            }
        }
    }
    __syncthreads();
    if (tid < 64) {
        float s = parts[0][tid];
#pragma unroll
        for (int w = 1; w < 16; w++) s += parts[w][tid];
        lse_sh[tid] = __builtin_amdgcn_logf(s) * LN2;  // v_log_f32 = log2
    }
    __syncthreads();

    // Write blank (col 0) and emit (target col); bias applied inline here.
#pragma unroll
    for (int mt = 0; mt < 4; mt++) {
#pragma unroll
        for (int j = 0; j < 4; j++) {
            int lr = mt * 16 + (lane >> 4) * 4 + j;
            int skb = skb_sh[lr];
            if (skb < 0) continue;
            int tc = tgt_sh[lr];
            bool isblank = (wave == 0) && (lrow == 0);
            bool isemit = (tc >= 0) && ((tc >> 6) == wave) && ((tc & 15) == lrow);
            if (isblank || isemit) {
                float lse = lse_sh[lr];
                if (isblank)
                    bsk[skb] = fmaf(boL[0], LN2, acc[mt][0][j]) - lse;
                if (isemit) {
                    int ntl = (tc >> 4) & 3;
                    float v = fmaf(boL[0], LN2, acc[mt][0][j]);
#pragma unroll
                    for (int nt = 1; nt < 4; nt++)
                        if (nt == ntl) v = fmaf(boL[nt], LN2, acc[mt][nt][j]);
                    esk[skb] = v - lse;
                }
            }
        }
    }
}

// ---------------------------------------------------------------------------
// Alpha recursion, u-chunk x2, 16-deep prefetch ring (slack > HBM latency).
// __launch_bounds__(256,1): full register budget, ring stays in VGPRs.
// ---------------------------------------------------------------------------
__global__ __launch_bounds__(256, 1) void alpha_c2_kernel(
    const float* __restrict__ bsk, const float* __restrict__ esk,
    const int* __restrict__ enc_len, const int* __restrict__ tgt_len,
    float* __restrict__ out) {
    __shared__ float ll_sh[B_];
    const int tid = threadIdx.x;
    const int b = tid >> 6;
    const int l = tid & 63;
    const float* Bp = bsk + b * (NDIAG * DSTR);
    const float* Ep = esk + b * (NDIAG * DSTR);
    const int el = enc_len[b];
    const int tl = tgt_len[b];
    const int dfin = el - 1 + tl;

    const int u0 = 2 * l;
    const bool ok0 = (u0 <= U_);
    const bool ok1 = (u0 + 1 <= U_);
    const int uc = ok0 ? u0 : 0;

    float A0 = (l == 0) ? 0.0f : -INFINITY;
    float A1 = -INFINITY;

    float2 rb[16], re[16];
#pragma unroll
    for (int k = 0; k < 16; k++) {
        rb[k] = *(const float2*)&Bp[k * DSTR + uc];
        re[k] = *(const float2*)&Ep[k * DSTR + uc];
    }

    for (int dc = 1; dc <= 289; dc += 16) {
#pragma unroll
        for (int q = 0; q < 16; q++) {
            const int d = dc + q;  // (dc-1)%16==0 -> static slot indices
            if (d > NDIAG - 1) continue;
            const int sc = q;             // (d-1)&15
            const int sm = (q + 1) & 15;  // d&15
            float2 cb = rb[sc], ce = re[sc];
            float2 mb = rb[sm];
            int dn = d + 15;
            if (dn > NDIAG - 1) dn = NDIAG - 1;
            rb[sc] = *(const float2*)&Bp[dn * DSTR + uc];
            re[sc] = *(const float2*)&Ep[dn * DSTR + uc];

            float s = A1 + ce.y;
            float sn = __shfl_up(s, 1, 64);

            float va0 = A0 + cb.x;
            float vb0 = (l >= 1) ? sn : -INFINITY;
            float va1 = A1 + cb.y;
            float vb1 = A0 + ce.x;

            float M0 = fmaxf(va0, vb0);
            float n0 = (M0 == -INFINITY)
                           ? -INFINITY
                           : M0 + __logf(1.0f + __expf(fminf(va0, vb0) - M0));
            float M1 = fmaxf(va1, vb1);
            float n1 = (M1 == -INFINITY)
                           ? -INFINITY
                           : M1 + __logf(1.0f + __expf(fminf(va1, vb1) - M1));

            const int t0 = d - u0;
            if (!ok0 || t0 < 0 || t0 >= T_) n0 = -INFINITY;
            if (!ok1 || (t0 - 1) < 0 || (t0 - 1) >= T_) n1 = -INFINITY;

            if (d == dfin) {
                if (tl == u0) ll_sh[b] = n0 + mb.x;
                if (tl == u0 + 1) ll_sh[b] = n1 + mb.y;
            }
            A0 = n0;
            A1 = n1;
        }
    }
    __syncthreads();
    if (tid == 0)
        out[0] = -0.25f * (ll_sh[0] + ll_sh[1] + ll_sh[2] + ll_sh[3]);
}

extern "C" void kernel_launch(void* const* d_in, const int* in_sizes, int n_in,
                              void* d_out, int out_size, void* d_ws, size_t ws_size,
                              hipStream_t stream) {
    const float* enc_out = (const float*)d_in[0];
    const float* dec_out = (const float*)d_in[1];
    const float* W_enc = (const float*)d_in[2];
    const float* b_enc = (const float*)d_in[3];
    const float* W_dec = (const float*)d_in[4];
    const float* b_dec = (const float*)d_in[5];
    const float* W_out = (const float*)d_in[6];
    const float* b_out = (const float*)d_in[7];
    const int* targets = (const int*)d_in[8];
    const int* enc_len = (const int*)d_in[9];
    const int* tgt_len = (const int*)d_in[10];

    float* ws = (float*)d_ws;
    float* enc_p = ws;                          // 256000 f32
    float* dec_p = enc_p + B_ * T_ * J_;        // 129280 f32
    float* bsk = dec_p + B_ * (U_ + 1) * J_;    // 124800 f32
    float* esk = bsk + B_ * NDIAG * DSTR;       // 124800 f32
    ushort* Wt = (ushort*)(esk + B_ * NDIAG * DSTR);  // 327680 bf16

    prep_kernel<<<140, 640, 0, stream>>>(enc_out, dec_out, W_enc, b_enc,
                                         W_dec, b_dec, W_out, enc_p, dec_p, Wt);

    joint_mfma<<<(M_TOT + 63) / 64, 1024, 0, stream>>>(
        enc_p, dec_p, Wt, b_out, targets, bsk, esk);

    alpha_c2_kernel<<<1, 256, 0, stream>>>(bsk, esk, enc_len, tgt_len,
                                           (float*)d_out);
}